// Round 14
// baseline (270.778 us; speedup 1.0000x reference)
//
#include <hip/hip_runtime.h>
#include <hip/hip_fp16.h>

#define DD 64
#define NUM_GRAPHS 64
#define AGG_BLOCKS 2048
#define EB 512          // edge-blocks for hist/scatter passes
#define BINW 128        // nodes per bin (128 -> 2x bincsr block parallelism)
#define BINSH 7         // log2(BINW)
#define MAXNB 1024      // LDS capacity for bin counters (NB=782 fits)
#define EBIN_CAP 3072   // max edges per bin staged in LDS (mean 2046, sd ~45)
#define SPAD 64         // pad (srcidx zeros / epku garbage-ok) for unconditional prefetch

typedef _Float16 h2_t __attribute__((ext_vector_type(2)));

__device__ __forceinline__ float fdot2u(unsigned a, unsigned b, float c) {
    return __builtin_amdgcn_fdot2(__builtin_bit_cast(h2_t, a),
                                  __builtin_bit_cast(h2_t, b), c, false);
}

// half payload of a packed meta word -> float
#define MDLO(m) __half2float(__ushort_as_half((unsigned short)((m) & 0xFFFF)))

// ---- v_fma_mix_f32: acc(f32) += f16(lo/hi of r) * 1.0 (agg3 —
//      measured faster there; agg2 measured faster with cvt+add) ----
__device__ __forceinline__ float fmixlo(float a, unsigned r) {
    float o;
    asm("v_fma_mix_f32 %0, %1, 1.0, %2 op_sel_hi:[1,0,0]"
        : "=v"(o) : "v"(r), "v"(a));
    return o;
}
__device__ __forceinline__ float fmixhi(float a, unsigned r) {
    float o;
    asm("v_fma_mix_f32 %0, %1, 1.0, %2 op_sel:[1,0,0] op_sel_hi:[1,0,0]"
        : "=v"(o) : "v"(r), "v"(a));
    return o;
}

// ---- pass A: per-edge-block histogram over bins (LDS atomics only) ----
__global__ __launch_bounds__(256) void k_hist(const int* __restrict__ col,
                                              int* __restrict__ H, int E, int NB, int CE) {
    __shared__ int h[MAXNB];
    int eb = blockIdx.x, t = threadIdx.x;
    for (int i = t; i < NB; i += 256) h[i] = 0;
    __syncthreads();
    int e0 = eb * CE, e1 = min(E, e0 + CE);
    for (int e = e0 + t; e < e1; e += 256) atomicAdd(&h[col[e] >> BINSH], 1);
    __syncthreads();
    for (int i = t; i < NB; i += 256) H[eb * NB + i] = h[i];
}

// ---- pass B1: per-bin exclusive scan over edge-blocks ----
__global__ __launch_bounds__(256) void k_scanA(int* __restrict__ H,
                                               int* __restrict__ bintot, int NB) {
    __shared__ int s[256];
    int b = blockIdx.x, t = threadIdx.x;
    int i0 = (2 * t) * NB + b, i1 = (2 * t + 1) * NB + b;
    int v0 = H[i0], v1 = H[i1];
    int tot = v0 + v1;
    s[t] = tot;
    __syncthreads();
    for (int off = 1; off < 256; off <<= 1) {
        int tv = (t >= off) ? s[t - off] : 0;
        __syncthreads();
        s[t] += tv;
        __syncthreads();
    }
    int excl = s[t] - tot;
    H[i0] = excl;
    H[i1] = excl + v0;
    if (t == 255) bintot[b] = s[255];
}

// ---- pass B2: scan bin totals (512 threads x 2 elements; NB <= 1024).
//      Also zeroes the srcidx pad (replaces a memset launch). ----
__global__ void k_scanB(const int* __restrict__ bintot, int* __restrict__ binstart,
                        int* __restrict__ srcidx, int E, int NB) {
    __shared__ int s[512];
    int t = threadIdx.x;
    if (t < SPAD) srcidx[E + t] = 0;          // pad: prefetches past E -> node 0
    int i0 = 2 * t, i1 = 2 * t + 1;
    int v0 = (i0 < NB) ? bintot[i0] : 0;
    int v1 = (i1 < NB) ? bintot[i1] : 0;
    int tot = v0 + v1;
    s[t] = tot;
    __syncthreads();
    for (int off = 1; off < 512; off <<= 1) {
        int tv = (t >= off) ? s[t - off] : 0;
        __syncthreads();
        s[t] += tv;
        __syncthreads();
    }
    int excl = s[t] - tot;
    if (i0 < NB) binstart[i0] = excl;
    if (i1 < NB) binstart[i1] = excl + v0;
    if (t == 511) binstart[NB] = s[511];
}

// ---- pass C: scatter packed edges into bin-contiguous regions ----
__global__ __launch_bounds__(256) void k_scatbin(const int* __restrict__ row,
                                                 const int* __restrict__ col,
                                                 const int* __restrict__ H,
                                                 const int* __restrict__ binstart,
                                                 unsigned* __restrict__ binned,
                                                 int E, int NB, int CE) {
    __shared__ int off[MAXNB];
    int eb = blockIdx.x, t = threadIdx.x;
    for (int i = t; i < NB; i += 256) off[i] = binstart[i] + H[eb * NB + i];
    __syncthreads();
    int e0 = eb * CE, e1 = min(E, e0 + CE);
    for (int e = e0 + t; e < e1; e += 256) {
        int c = col[e], r = row[e];
        int slot = atomicAdd(&off[c >> BINSH], 1);
        binned[slot] = ((unsigned)(c & (BINW - 1)) << 24) | (unsigned)r;
    }
}

// ---- pass D: per-bin CSR finalize in LDS (BINW=128: 782 blocks, fused
//      load+hist pass, 25.5KB LDS) ----
__global__ __launch_bounds__(256) void k_bincsr(const unsigned* __restrict__ binned,
                                                const int* __restrict__ binstart,
                                                const int* __restrict__ nt,
                                                int* __restrict__ srcidx,
                                                int* __restrict__ rowptr,
                                                float* __restrict__ dinv,
                                                int2* __restrict__ pk, int N, int NB) {
    __shared__ unsigned arr[EBIN_CAP];
    __shared__ int sorted_[EBIN_CAP];
    __shared__ int cnt[BINW];
    __shared__ int base[BINW];
    __shared__ int cursor[BINW];
    int b = blockIdx.x, t = threadIdx.x;
    int s0 = binstart[b], s1 = binstart[b + 1];
    int binsz = s1 - s0;
    if (binsz > EBIN_CAP) binsz = EBIN_CAP;
    if (t < BINW) cnt[t] = 0;
    __syncthreads();
    for (int i = t; i < binsz; i += 256) {      // fused load + histogram
        unsigned val = binned[s0 + i];
        arr[i] = val;
        atomicAdd(&cnt[val >> 24], 1);
    }
    __syncthreads();
    int v = (t < BINW) ? cnt[t] : 0;
    float di = rsqrtf((float)v + 1.0f);   // +1 = self loop
    if (t < BINW) base[t] = v;
    __syncthreads();
    for (int off = 1; off < BINW; off <<= 1) {
        int tv = (t >= off && t < BINW) ? base[t - off] : 0;
        __syncthreads();
        if (t < BINW) base[t] += tv;
        __syncthreads();
    }
    int excl = (t < BINW) ? (base[t] - v) : 0;
    __syncthreads();
    if (t < BINW) { base[t] = excl; cursor[t] = excl; }
    __syncthreads();
    for (int i = t; i < binsz; i += 256) {
        unsigned val = arr[i];
        int pos = atomicAdd(&cursor[val >> 24], 1);
        sorted_[pos] = (int)(val & 0xFFFFFF);
    }
    __syncthreads();
    for (int i = t; i < binsz; i += 256) srcidx[s0 + i] = sorted_[i];
    int node = b * BINW + t;
    if (t < BINW && node < N) {
        rowptr[node] = s0 + base[t];
        dinv[node] = di;
        pk[node] = make_int2(nt[node], __float_as_int(di));
    }
    if (b == NB - 1 && t == 0) rowptr[N] = s1;
}

// ---- per-edge packed operand in CSR order (layer 1: type[src], dinv[src]).
//      Also zeroes pool (replaces a memset launch; runs before agg3). ----
__global__ void k_buildepk(const int* __restrict__ srcidx, const int2* __restrict__ pk,
                           unsigned* __restrict__ epku, float* __restrict__ pool, int E) {
    int i = blockIdx.x * blockDim.x + threadIdx.x;
    if (i < NUM_GRAPHS * DD) pool[i] = 0.f;
    if (i >= E) return;
    int2 p = pk[srcidx[i]];
    epku[i] = ((unsigned)p.x << 16) |
              (unsigned)__half_as_ushort(__float2half(__int_as_float(p.y)));
}

// ---- embW1 = emb_table @ W1 ----
__global__ void k_embW1(const float* __restrict__ emb, const float* __restrict__ W1,
                        float* __restrict__ embW1, int V) {
    __shared__ float er[DD];
    int v = blockIdx.x, j = threadIdx.x;
    er[j] = emb[v * DD + j];
    __syncthreads();
    float acc = 0.0f;
    #pragma unroll
    for (int d = 0; d < DD; ++d) acc += er[d] * W1[d * DD + j];
    embW1[v * DD + j] = acc;
}

// ---- pack W (64x64 f32) into half2 pairs: Wpk[p*64+j] = {W[2p][j], W[2p+1][j]} ----
__global__ void k_packW(const float* __restrict__ W, unsigned* __restrict__ Wpk) {
    int t = blockIdx.x * blockDim.x + threadIdx.x;
    if (t >= 32 * DD) return;
    int p = t >> 6, j = t & 63;
    __half2 h = __floats2half2_rn(W[(2 * p) * DD + j], W[(2 * p + 1) * DD + j]);
    Wpk[t] = __builtin_bit_cast(unsigned, h);
}

// ======================= quarter-wave gather (4 groups x 16 lanes) ==========
// lane l owns features [4l,4l+4) via uint2 (8B); 4-deep per-lane load pipeline.
// accumulate via v_fma_mix (measured faster for agg3). NO index prefetch:
// agg3's nodes are adjacent so srcidx streams are L1-warm (round-11 lesson).
__device__ __forceinline__ void acc_h4(float4& a, uint2 r) {
    a.x = fmixlo(a.x, r.x); a.y = fmixhi(a.y, r.x);
    a.z = fmixlo(a.z, r.y); a.w = fmixhi(a.w, r.y);
}

// partial sum (NO cross-group reduce) — caller reduces when needed
__device__ __forceinline__ float4 gather_partial_q(const int* __restrict__ srcidx,
                                                   const __half* __restrict__ Hs,
                                                   int s, int e, int g, int l) {
    float4 A = {0,0,0,0}, B = {0,0,0,0}, C = {0,0,0,0}, D = {0,0,0,0};
    int k = s;
    int kend = s + ((e - s) & ~15);
    if (k < kend) {
        uint2 r0 = *(const uint2*)(Hs + (long)srcidx[k + g] * DD + 4 * l);
        uint2 r1 = *(const uint2*)(Hs + (long)srcidx[k + 4 + g] * DD + 4 * l);
        uint2 r2 = *(const uint2*)(Hs + (long)srcidx[k + 8 + g] * DD + 4 * l);
        uint2 r3 = *(const uint2*)(Hs + (long)srcidx[k + 12 + g] * DD + 4 * l);
        k += 16;
        for (; k < kend; k += 16) {
            uint2 n0 = *(const uint2*)(Hs + (long)srcidx[k + g] * DD + 4 * l);
            uint2 n1 = *(const uint2*)(Hs + (long)srcidx[k + 4 + g] * DD + 4 * l);
            uint2 n2 = *(const uint2*)(Hs + (long)srcidx[k + 8 + g] * DD + 4 * l);
            uint2 n3 = *(const uint2*)(Hs + (long)srcidx[k + 12 + g] * DD + 4 * l);
            acc_h4(A, r0); acc_h4(B, r1); acc_h4(C, r2); acc_h4(D, r3);
            r0 = n0; r1 = n1; r2 = n2; r3 = n3;
        }
        acc_h4(A, r0); acc_h4(B, r1); acc_h4(C, r2); acc_h4(D, r3);
    }
    for (; k < e; k += 4) {
        if (k + g < e) {
            uint2 rr = *(const uint2*)(Hs + (long)srcidx[k + g] * DD + 4 * l);
            acc_h4(A, rr);
        }
    }
    A.x += B.x + C.x + D.x; A.y += B.y + C.y + D.y;
    A.z += B.z + C.z + D.z; A.w += B.w + C.w + D.w;
    return A;
}

// ======================= eighth-wave gather (8 groups x 8 lanes) ============
// lane l owns features [8l,8l+8) via one uint4 (16B) load per row.
// cvt+add accumulate (measured faster than fma_mix for agg2: 59.1 vs 61.2 us).
__device__ __forceinline__ void acc_h8(float4& A, float4& B, uint4 r) {
    float2 f0 = __half22float2(*(const __half2*)&r.x);
    float2 f1 = __half22float2(*(const __half2*)&r.y);
    float2 f2 = __half22float2(*(const __half2*)&r.z);
    float2 f3 = __half22float2(*(const __half2*)&r.w);
    A.x += f0.x; A.y += f0.y; A.z += f1.x; A.w += f1.y;
    B.x += f2.x; B.y += f2.y; B.z += f3.x; B.w += f3.y;
}

// r0/r1 = PRE-LOADED first-round rows (issued during the previous node's
// epilogue); pi2/pi3 = tail indices at q = s + ((e-s)&~15), prefetched a
// full node ahead. No srcidx->row serial hop anywhere on the critical path.
__device__ __forceinline__ void gather_sum_8r(const int* __restrict__ srcidx,
                                              const __half* __restrict__ Hs,
                                              int s, int e, int g, int l,
                                              float4& A, float4& B,
                                              uint4 r0, uint4 r1, int pi2, int pi3) {
    float4 A1 = {0.f, 0.f, 0.f, 0.f}, B1 = {0.f, 0.f, 0.f, 0.f};
    int k = s;
    int kend = s + ((e - s) & ~15);
    if (k < kend) {
        k += 16;
        for (; k < kend; k += 16) {
            uint4 n0 = *(const uint4*)(Hs + (long)srcidx[k + g] * DD + 8 * l);
            uint4 n1 = *(const uint4*)(Hs + (long)srcidx[k + 8 + g] * DD + 8 * l);
            acc_h8(A, B, r0);
            acc_h8(A1, B1, r1);
            r0 = n0; r1 = n1;
        }
        acc_h8(A, B, r0);
        acc_h8(A1, B1, r1);
    }
    if (k + 8 <= e) {                       // one more full round of 8 (idx prefetched)
        uint4 r = *(const uint4*)(Hs + (long)pi2 * DD + 8 * l);
        acc_h8(A, B, r);
        k += 8;
        pi2 = pi3;                          // tail (if any) uses the second tail index
    }
    if (k + g < e) {                        // tail < 8 edges (idx prefetched)
        uint4 r = *(const uint4*)(Hs + (long)pi2 * DD + 8 * l);
        acc_h8(A1, B1, r);
    }
    A.x += A1.x; A.y += A1.y; A.z += A1.z; A.w += A1.w;
    B.x += B1.x; B.y += B1.y; B.z += B1.z; B.w += B1.w;
}

// ---- layer-1, quarter-wave over LDS ew table; next-node epku prefetch
//      covering BOTH the first round (pu0/pu1) and the tail (pu2/pu3). ----
__global__ __launch_bounds__(256, 4) void k_agg1_fused(const int* __restrict__ rowptr,
                                                    const unsigned* __restrict__ epku,
                                                    const int2* __restrict__ pk,
                                                    const float* __restrict__ embW1,
                                                    const float* __restrict__ b1,
                                                    __half* __restrict__ OUT, int N, int V) {
    __shared__ float ew[30 * DD];
    int tid = threadIdx.x;
    for (int k = tid; k < V * DD; k += 256) ew[k] = embW1[k];
    __syncthreads();
    int lane = tid & 63;
    int g = lane >> 4, l = lane & 15;
    float4 bq = *(const float4*)(b1 + 4 * l);
    int wstride = gridDim.x * 4;
    int node = __builtin_amdgcn_readfirstlane(blockIdx.x * 4 + (tid >> 6));
    int s = 0, e = 0;
    unsigned pu0 = 0, pu1 = 0, pu2 = 0, pu3 = 0;
    if (node < N) {
        s = rowptr[node]; e = rowptr[node + 1];
        int q1 = s + ((e - s) & ~7);
        pu0 = epku[s + g];  pu1 = epku[s + 4 + g];    // unconditional (SPAD)
        pu2 = epku[q1 + g]; pu3 = epku[q1 + 4 + g];
    }
#define P8(U0, U1) { \
        unsigned _u0 = (U0), _u1 = (U1); \
        int _t0 = _u0 >> 16, _t1 = _u1 >> 16; \
        float _d0 = MDLO(_u0), _d1 = MDLO(_u1); \
        float4 _w0 = *(const float4*)(ew + _t0 * DD + 4 * l); \
        float4 _w1 = *(const float4*)(ew + _t1 * DD + 4 * l); \
        acc.x += _w0.x * _d0 + _w1.x * _d1; \
        acc.y += _w0.y * _d0 + _w1.y * _d1; \
        acc.z += _w0.z * _d0 + _w1.z * _d1; \
        acc.w += _w0.w * _d0 + _w1.w * _d1; }
#define P4(U0) { \
        unsigned _u0 = (U0); \
        int _t0 = _u0 >> 16; \
        float _d0 = MDLO(_u0); \
        float4 _w0 = *(const float4*)(ew + _t0 * DD + 4 * l); \
        acc.x += _w0.x * _d0; acc.y += _w0.y * _d0; \
        acc.z += _w0.z * _d0; acc.w += _w0.w * _d0; }
    while (node < N) {
        int nn = node + wstride;
        int ns = 0, ne = 0;
        if (nn < N) { ns = rowptr[nn]; ne = rowptr[nn + 1]; }
        int2 pc = pk[node];                       // epilogue data, off the chain
        float4 acc = {0.f, 0.f, 0.f, 0.f};
        int k = s;
        if (k + 8 <= e) {
            P8(pu0, pu1);
            k += 8;
            for (; k + 8 <= e; k += 8) P8(epku[k + g], epku[k + 4 + g]);
        }
        if (k + 4 <= e) { P4(pu2); k += 4; pu2 = pu3; }   // tail values prefetched
        if (k + g < e)  { P4(pu2); }
        unsigned npu0 = 0, npu1 = 0, npu2 = 0, npu3 = 0;  // next-node prefetch
        if (nn < N) {
            int q1 = ns + ((ne - ns) & ~7);
            npu0 = epku[ns + g];  npu1 = epku[ns + 4 + g];
            npu2 = epku[q1 + g];  npu3 = epku[q1 + 4 + g];
        }
        acc.x += __shfl_xor(acc.x, 16, 64); acc.x += __shfl_xor(acc.x, 32, 64);
        acc.y += __shfl_xor(acc.y, 16, 64); acc.y += __shfl_xor(acc.y, 32, 64);
        acc.z += __shfl_xor(acc.z, 16, 64); acc.z += __shfl_xor(acc.z, 32, 64);
        acc.w += __shfl_xor(acc.w, 16, 64); acc.w += __shfl_xor(acc.w, 32, 64);
        float dc = __int_as_float(pc.y);
        float4 wc = *(const float4*)(ew + pc.x * DD + 4 * l);
        float4 v;
        v.x = fmaxf((acc.x + wc.x * dc) * dc + bq.x, 0.f) * dc;
        v.y = fmaxf((acc.y + wc.y * dc) * dc + bq.y, 0.f) * dc;
        v.z = fmaxf((acc.z + wc.z * dc) * dc + bq.z, 0.f) * dc;
        v.w = fmaxf((acc.w + wc.w * dc) * dc + bq.w, 0.f) * dc;
        if (g == 0) {
            __half2 h0 = __floats2half2_rn(v.x, v.y);
            __half2 h1 = __floats2half2_rn(v.z, v.w);
            uint2 st;
            st.x = __builtin_bit_cast(unsigned, h0);
            st.y = __builtin_bit_cast(unsigned, h1);
            *(uint2*)(OUT + (long)node * DD + 4 * l) = st;
        }
        node = nn; s = ns; e = ne;
        pu0 = npu0; pu1 = npu1; pu2 = npu2; pu3 = npu3;
    }
#undef P8
#undef P4
}

// ---- layer-2: eighth-wave gather + W2 matmul. Next-node prefetch now
//      carries the first-round ROWS (cr0/cr1, issued before the epilogue so
//      their latency hides under the reduce+matmul) plus tail indices. ----
__global__ __launch_bounds__(256, 4) void k_agg2_fused(const int* __restrict__ rowptr,
                                                    const int* __restrict__ srcidx,
                                                    const float* __restrict__ dinv,
                                                    const __half* __restrict__ Hs,
                                                    const float* __restrict__ b2,
                                                    const unsigned* __restrict__ W2pk,
                                                    __half* __restrict__ OUT, int N) {
    int tid = threadIdx.x;
    int lane = tid & 63;
    int g = lane >> 3, l = lane & 7;
    unsigned Wc[32];
    #pragma unroll
    for (int p = 0; p < 32; ++p) Wc[p] = W2pk[p * DD + lane];
    float bl = b2[lane];              // bias on OUTPUT feature (post-matmul)
    int wstride = gridDim.x * 4;
    int node = __builtin_amdgcn_readfirstlane(blockIdx.x * 4 + (tid >> 6));
    int s = 0, e = 0;
    int pi2 = 0, pi3 = 0;
    uint4 cr0 = {0, 0, 0, 0}, cr1 = {0, 0, 0, 0};
    if (node < N) {
        s = rowptr[node]; e = rowptr[node + 1];
        int q = s + ((e - s) & ~15);
        int i0 = srcidx[s + g], i1 = srcidx[s + 8 + g];  // unconditional (SPAD->0)
        pi2 = srcidx[q + g];  pi3 = srcidx[q + 8 + g];
        cr0 = *(const uint4*)(Hs + (long)i0 * DD + 8 * l);
        cr1 = *(const uint4*)(Hs + (long)i1 * DD + 8 * l);
    }
    while (node < N) {
        int nn = node + wstride;
        int ns = 0, ne = 0;
        if (nn < N) { ns = rowptr[nn]; ne = rowptr[nn + 1]; }   // prefetch next node
        float dc = dinv[node];                                   // prefetch epilogue data
        uint4 sr = *(const uint4*)(Hs + (long)node * DD + 8 * l);
        float4 A = {0.f, 0.f, 0.f, 0.f}, B = {0.f, 0.f, 0.f, 0.f};
        gather_sum_8r(srcidx, Hs, s, e, g, l, A, B, cr0, cr1, pi2, pi3);
        // next-node prefetch: tail indices + FIRST-ROUND ROWS (latency hidden
        // under the reduce + matmul epilogue below)
        int npi2 = 0, npi3 = 0;
        uint4 nr0 = {0, 0, 0, 0}, nr1 = {0, 0, 0, 0};
        if (nn < N) {
            int qn = ns + ((ne - ns) & ~15);
            int i0 = srcidx[ns + g], i1 = srcidx[ns + 8 + g];
            npi2 = srcidx[qn + g];  npi3 = srcidx[qn + 8 + g];
            nr0 = *(const uint4*)(Hs + (long)i0 * DD + 8 * l);
            nr1 = *(const uint4*)(Hs + (long)i1 * DD + 8 * l);
        }
        // reduce across the 8 groups (g = lane bits 3..5)
        #pragma unroll
        for (int m = 8; m <= 32; m <<= 1) {
            A.x += __shfl_xor(A.x, m, 64); A.y += __shfl_xor(A.y, m, 64);
            A.z += __shfl_xor(A.z, m, 64); A.w += __shfl_xor(A.w, m, 64);
            B.x += __shfl_xor(B.x, m, 64); B.y += __shfl_xor(B.y, m, 64);
            B.z += __shfl_xor(B.z, m, 64); B.w += __shfl_xor(B.w, m, 64);
        }
        float2 s0 = __half22float2(*(const __half2*)&sr.x);
        float2 s1 = __half22float2(*(const __half2*)&sr.y);
        float2 s2 = __half22float2(*(const __half2*)&sr.z);
        float2 s3 = __half22float2(*(const __half2*)&sr.w);
        float t0 = (A.x + s0.x) * dc, t1 = (A.y + s0.y) * dc;
        float t2 = (A.z + s1.x) * dc, t3 = (A.w + s1.y) * dc;
        float t4 = (B.x + s2.x) * dc, t5 = (B.y + s2.y) * dc;
        float t6 = (B.z + s3.x) * dc, t7 = (B.w + s3.y) * dc;
        // pack: lane l (0..7) holds pairs (t[8l+2q], t[8l+2q+1]) in vp[q]
        int vp0 = __builtin_bit_cast(int, __floats2half2_rn(t0, t1));
        int vp1 = __builtin_bit_cast(int, __floats2half2_rn(t2, t3));
        int vp2 = __builtin_bit_cast(int, __floats2half2_rn(t4, t5));
        int vp3 = __builtin_bit_cast(int, __floats2half2_rn(t6, t7));
        // (t @ W2)[lane]: pair p lives in lane p>>2, slot p&3
        float o0 = 0.f, o1 = 0.f, o2 = 0.f, o3 = 0.f;
        #pragma unroll
        for (int p = 0; p < 32; p += 4) {
            o0 = fdot2u((unsigned)__builtin_amdgcn_readlane(vp0, p >> 2), Wc[p + 0], o0);
            o1 = fdot2u((unsigned)__builtin_amdgcn_readlane(vp1, p >> 2), Wc[p + 1], o1);
            o2 = fdot2u((unsigned)__builtin_amdgcn_readlane(vp2, p >> 2), Wc[p + 2], o2);
            o3 = fdot2u((unsigned)__builtin_amdgcn_readlane(vp3, p >> 2), Wc[p + 3], o3);
        }
        float u = (o0 + o1) + (o2 + o3);
        float v2 = fmaxf(u + bl, 0.f);
        OUT[(long)node * DD + lane] = __float2half(v2 * dc);   // v2s = v2*dinv
        node = nn; s = ns; e = ne;
        pi2 = npi2; pi3 = npi3; cr0 = nr0; cr1 = nr1;
    }
}

// ---- reduce per-group (4-group) pool partials, then atomics (g==0 lanes) ----
__device__ __forceinline__ void flush_pool_q(float4& PA, float* __restrict__ pool,
                                             int gcur, int g, int l) {
    gcur &= (NUM_GRAPHS - 1);   // defensive: guarantees in-bounds atomic target
    PA.x += __shfl_xor(PA.x, 16, 64); PA.x += __shfl_xor(PA.x, 32, 64);
    PA.y += __shfl_xor(PA.y, 16, 64); PA.y += __shfl_xor(PA.y, 32, 64);
    PA.z += __shfl_xor(PA.z, 16, 64); PA.z += __shfl_xor(PA.z, 32, 64);
    PA.w += __shfl_xor(PA.w, 16, 64); PA.w += __shfl_xor(PA.w, 32, 64);
    if (g == 0) {
        atomicAdd(&pool[gcur * DD + 4 * l + 0], PA.x);
        atomicAdd(&pool[gcur * DD + 4 * l + 1], PA.y);
        atomicAdd(&pool[gcur * DD + 4 * l + 2], PA.z);
        atomicAdd(&pool[gcur * DD + 4 * l + 3], PA.w);
    }
}

// ---- layer-3 + pooling in v2-space: y = dc*(Σ v2s + self); pool[batch] += y.
//      Quarter-wave gather (4-deep load pipeline, known-good round-10 form) +
//      per-group partial pool accumulators. ----
__global__ __launch_bounds__(256, 4) void k_agg3_pool(const int* __restrict__ rowptr,
                                                   const int* __restrict__ srcidx,
                                                   const float* __restrict__ dinv,
                                                   const __half* __restrict__ Hs,
                                                   const int* __restrict__ batch,
                                                   float* __restrict__ pool,
                                                   int N, int chunk) {
    int tid = threadIdx.x;
    int lane = tid & 63;
    int g = lane >> 4, l = lane & 15;
    int w = __builtin_amdgcn_readfirstlane(blockIdx.x * 4 + (tid >> 6));
    int start = w * chunk;
    if (start >= N) return;
    int endn = min(N, start + chunk);
    int gcur = batch[start];
    float4 PA = {0.f, 0.f, 0.f, 0.f};
    int s = rowptr[start];                 // contiguous chunk: s = previous e
    for (int node = start; node < endn; ++node) {
        int e = rowptr[node + 1];
        float dc = dinv[node];
        int gb = batch[node];
        uint2 sr = *(const uint2*)(Hs + (long)node * DD + 4 * l);  // early, overlaps gather
        float4 A = gather_partial_q(srcidx, Hs, s, e, g, l);
        if (g == 0) {                      // add self exactly once (group 0)
            A.x = fmixlo(A.x, sr.x); A.y = fmixhi(A.y, sr.x);
            A.z = fmixlo(A.z, sr.y); A.w = fmixhi(A.w, sr.y);
        }
        if (gb != gcur) {
            flush_pool_q(PA, pool, gcur, g, l);
            gcur = gb;
            PA.x = dc * A.x; PA.y = dc * A.y; PA.z = dc * A.z; PA.w = dc * A.w;
        } else {
            PA.x += dc * A.x; PA.y += dc * A.y; PA.z += dc * A.z; PA.w += dc * A.w;
        }
        s = e;
    }
    flush_pool_q(PA, pool, gcur, g, l);
}

// ---- final: per-graph W3 matmul (f32) + b3, mean, L2 normalize ----
__global__ void k_final(const float* __restrict__ pool, const int* __restrict__ batch,
                        const float* __restrict__ W3, const float* __restrict__ b3,
                        float* __restrict__ out, int N) {
    __shared__ float pr[DD];
    int g = blockIdx.x, j = threadIdx.x;
    pr[j] = pool[g * DD + j];
    __syncthreads();
    int lo = 0, hi = N;
    while (lo < hi) { int m = (lo + hi) >> 1; if (batch[m] < g) lo = m + 1; else hi = m; }
    int lo2 = lo; hi = N;
    while (lo2 < hi) { int m = (lo2 + hi) >> 1; if (batch[m] < g + 1) lo2 = m + 1; else hi = m; }
    float cnt = fmaxf((float)(lo2 - lo), 1.0f);
    float acc = 0.0f;
    #pragma unroll
    for (int d = 0; d < DD; ++d) acc += pr[d] * W3[d * DD + j];
    float v = acc / cnt + b3[j];
    float sq = v * v;
    #pragma unroll
    for (int off = 32; off > 0; off >>= 1) sq += __shfl_down(sq, off, 64);
    float nrm = __shfl(sq, 0, 64);
    out[g * DD + j] = v / sqrtf(nrm);
}

extern "C" void kernel_launch(void* const* d_in, const int* in_sizes, int n_in,
                              void* d_out, int out_size, void* d_ws, size_t ws_size,
                              hipStream_t stream) {
    const int*   node_types = (const int*)d_in[0];
    const int*   edge_index = (const int*)d_in[1];
    const int*   batch      = (const int*)d_in[2];
    const float* emb        = (const float*)d_in[3];
    const float* W1 = (const float*)d_in[4];
    const float* b1 = (const float*)d_in[5];
    const float* W2 = (const float*)d_in[6];
    const float* b2 = (const float*)d_in[7];
    const float* W3 = (const float*)d_in[8];
    const float* b3 = (const float*)d_in[9];
    const int N = in_sizes[0];
    const int E = in_sizes[1] / 2;
    const int V = in_sizes[3] / DD;
    const int* row = edge_index;
    const int* col = edge_index + E;
    const long ND = (long)N * DD;
    const int NB = (N + BINW - 1) / BINW;
    const int CE = (E + EB - 1) / EB;

    // workspace layout (srcidx/epku padded +SPAD for unconditional prefetch)
    char* p = (char*)d_ws;
    __half*   hsA     = (__half*)p;       p += ND * sizeof(__half);
    __half*   hsB     = (__half*)p;       p += ND * sizeof(__half);
    int*      srcidx  = (int*)p;          p += (size_t)(E + SPAD) * sizeof(int);
    unsigned* epku    = (unsigned*)p;     p += (size_t)(E + SPAD) * sizeof(unsigned);
    unsigned* binned  = (unsigned*)p;     p += (size_t)E * sizeof(unsigned);
    int*      H       = (int*)p;          p += (size_t)EB * NB * sizeof(int);
    int*      bintot  = (int*)p;          p += (size_t)(NB + 4) * sizeof(int);
    int*      binstart= (int*)p;          p += (size_t)(NB + 4) * sizeof(int);
    float*    dinv    = (float*)p;        p += (size_t)N * sizeof(float);
    int2*     pk      = (int2*)p;         p += (size_t)N * sizeof(int2);
    int*      rowptr  = (int*)p;          p += (size_t)(N + 4) * sizeof(int);
    float*    pool    = (float*)p;        p += (size_t)NUM_GRAPHS * DD * sizeof(float);
    float*    embW1   = (float*)p;        p += (size_t)V * DD * sizeof(float);
    unsigned* W2pk    = (unsigned*)p;     p += 32 * DD * sizeof(unsigned);

    // ---- atomic-free sort-based CSR build (srcidx pad zeroed in k_scanB;
    //      pool zeroed in k_buildepk — no separate memset launches) ----
    k_hist<<<EB, 256, 0, stream>>>(col, H, E, NB, CE);
    k_scanA<<<NB, 256, 0, stream>>>(H, bintot, NB);
    k_scanB<<<1, 512, 0, stream>>>(bintot, binstart, srcidx, E, NB);
    k_scatbin<<<EB, 256, 0, stream>>>(row, col, H, binstart, binned, E, NB, CE);
    k_bincsr<<<NB, 256, 0, stream>>>(binned, binstart, node_types, srcidx, rowptr,
                                     dinv, pk, N, NB);
    k_buildepk<<<(E + 255) / 256, 256, 0, stream>>>(srcidx, pk, epku, pool, E);

    // ---- weight prep ----
    k_embW1<<<V, DD, 0, stream>>>(emb, W1, embW1, V);
    k_packW<<<8, 256, 0, stream>>>(W2, W2pk);

    // ---- layer 1 -> v1s fp16 (quarter-wave, no matmul) ----
    k_agg1_fused<<<AGG_BLOCKS, 256, 0, stream>>>(rowptr, epku, pk, embW1, b1,
                                                 hsA, N, V);
    // ---- layer 2: gather + W2 post-agg -> v2s fp16 ----
    k_agg2_fused<<<AGG_BLOCKS, 256, 0, stream>>>(rowptr, srcidx, dinv, hsA, b2, W2pk,
                                                 hsB, N);
    // ---- layer 3 + pooling in v2-space ----
    const int totalWaves = AGG_BLOCKS * 4;
    const int chunk = (N + totalWaves - 1) / totalWaves;
    k_agg3_pool<<<AGG_BLOCKS, 256, 0, stream>>>(rowptr, srcidx, dinv, hsB, batch,
                                                pool, N, chunk);
    // ---- per-graph W3 + b3 + mean + normalize ----
    k_final<<<NUM_GRAPHS, DD, 0, stream>>>(pool, batch, W3, b3, (float*)d_out, N);
}

// Round 15
// 264.925 us; speedup vs baseline: 1.0221x; 1.0221x over previous
//
#include <hip/hip_runtime.h>
#include <hip/hip_fp16.h>

#define DD 64
#define NUM_GRAPHS 64
#define AGG_BLOCKS 2048
#define EB 512          // edge-blocks for hist/scatter passes
#define BINW 128        // nodes per bin (128 -> 2x bincsr block parallelism)
#define BINSH 7         // log2(BINW)
#define MAXNB 1024      // LDS capacity for bin counters (NB=782 fits)
#define EBIN_CAP 3072   // max edges per bin staged in LDS (mean 2046, sd ~45)
#define SPAD 64         // pad (srcidx zeros / epku garbage-ok) for unconditional prefetch

typedef _Float16 h2_t __attribute__((ext_vector_type(2)));

__device__ __forceinline__ float fdot2u(unsigned a, unsigned b, float c) {
    return __builtin_amdgcn_fdot2(__builtin_bit_cast(h2_t, a),
                                  __builtin_bit_cast(h2_t, b), c, false);
}

// half payload of a packed meta word -> float
#define MDLO(m) __half2float(__ushort_as_half((unsigned short)((m) & 0xFFFF)))

// ---- v_fma_mix_f32: acc(f32) += f16(lo/hi of r) * 1.0 (agg3 —
//      measured faster there; agg2 measured faster with cvt+add) ----
__device__ __forceinline__ float fmixlo(float a, unsigned r) {
    float o;
    asm("v_fma_mix_f32 %0, %1, 1.0, %2 op_sel_hi:[1,0,0]"
        : "=v"(o) : "v"(r), "v"(a));
    return o;
}
__device__ __forceinline__ float fmixhi(float a, unsigned r) {
    float o;
    asm("v_fma_mix_f32 %0, %1, 1.0, %2 op_sel:[1,0,0] op_sel_hi:[1,0,0]"
        : "=v"(o) : "v"(r), "v"(a));
    return o;
}

// ---- pass A: per-edge-block histogram over bins (LDS atomics only) ----
__global__ __launch_bounds__(256) void k_hist(const int* __restrict__ col,
                                              int* __restrict__ H, int E, int NB, int CE) {
    __shared__ int h[MAXNB];
    int eb = blockIdx.x, t = threadIdx.x;
    for (int i = t; i < NB; i += 256) h[i] = 0;
    __syncthreads();
    int e0 = eb * CE, e1 = min(E, e0 + CE);
    for (int e = e0 + t; e < e1; e += 256) atomicAdd(&h[col[e] >> BINSH], 1);
    __syncthreads();
    for (int i = t; i < NB; i += 256) H[eb * NB + i] = h[i];
}

// ---- pass B1: per-bin exclusive scan over edge-blocks ----
__global__ __launch_bounds__(256) void k_scanA(int* __restrict__ H,
                                               int* __restrict__ bintot, int NB) {
    __shared__ int s[256];
    int b = blockIdx.x, t = threadIdx.x;
    int i0 = (2 * t) * NB + b, i1 = (2 * t + 1) * NB + b;
    int v0 = H[i0], v1 = H[i1];
    int tot = v0 + v1;
    s[t] = tot;
    __syncthreads();
    for (int off = 1; off < 256; off <<= 1) {
        int tv = (t >= off) ? s[t - off] : 0;
        __syncthreads();
        s[t] += tv;
        __syncthreads();
    }
    int excl = s[t] - tot;
    H[i0] = excl;
    H[i1] = excl + v0;
    if (t == 255) bintot[b] = s[255];
}

// ---- pass B2: scan bin totals (512 threads x 2 elements; NB <= 1024).
//      Also zeroes the srcidx pad (replaces a memset launch). ----
__global__ void k_scanB(const int* __restrict__ bintot, int* __restrict__ binstart,
                        int* __restrict__ srcidx, int E, int NB) {
    __shared__ int s[512];
    int t = threadIdx.x;
    if (t < SPAD) srcidx[E + t] = 0;          // pad: prefetches past E -> node 0
    int i0 = 2 * t, i1 = 2 * t + 1;
    int v0 = (i0 < NB) ? bintot[i0] : 0;
    int v1 = (i1 < NB) ? bintot[i1] : 0;
    int tot = v0 + v1;
    s[t] = tot;
    __syncthreads();
    for (int off = 1; off < 512; off <<= 1) {
        int tv = (t >= off) ? s[t - off] : 0;
        __syncthreads();
        s[t] += tv;
        __syncthreads();
    }
    int excl = s[t] - tot;
    if (i0 < NB) binstart[i0] = excl;
    if (i1 < NB) binstart[i1] = excl + v0;
    if (t == 511) binstart[NB] = s[511];
}

// ---- pass C: scatter packed edges into bin-contiguous regions ----
__global__ __launch_bounds__(256) void k_scatbin(const int* __restrict__ row,
                                                 const int* __restrict__ col,
                                                 const int* __restrict__ H,
                                                 const int* __restrict__ binstart,
                                                 unsigned* __restrict__ binned,
                                                 int E, int NB, int CE) {
    __shared__ int off[MAXNB];
    int eb = blockIdx.x, t = threadIdx.x;
    for (int i = t; i < NB; i += 256) off[i] = binstart[i] + H[eb * NB + i];
    __syncthreads();
    int e0 = eb * CE, e1 = min(E, e0 + CE);
    for (int e = e0 + t; e < e1; e += 256) {
        int c = col[e], r = row[e];
        int slot = atomicAdd(&off[c >> BINSH], 1);
        binned[slot] = ((unsigned)(c & (BINW - 1)) << 24) | (unsigned)r;
    }
}

// ---- pass D: per-bin CSR finalize in LDS (BINW=128: 782 blocks, fused
//      load+hist pass, 25.5KB LDS) ----
__global__ __launch_bounds__(256) void k_bincsr(const unsigned* __restrict__ binned,
                                                const int* __restrict__ binstart,
                                                const int* __restrict__ nt,
                                                int* __restrict__ srcidx,
                                                int* __restrict__ rowptr,
                                                float* __restrict__ dinv,
                                                int2* __restrict__ pk, int N, int NB) {
    __shared__ unsigned arr[EBIN_CAP];
    __shared__ int sorted_[EBIN_CAP];
    __shared__ int cnt[BINW];
    __shared__ int base[BINW];
    __shared__ int cursor[BINW];
    int b = blockIdx.x, t = threadIdx.x;
    int s0 = binstart[b], s1 = binstart[b + 1];
    int binsz = s1 - s0;
    if (binsz > EBIN_CAP) binsz = EBIN_CAP;
    if (t < BINW) cnt[t] = 0;
    __syncthreads();
    for (int i = t; i < binsz; i += 256) {      // fused load + histogram
        unsigned val = binned[s0 + i];
        arr[i] = val;
        atomicAdd(&cnt[val >> 24], 1);
    }
    __syncthreads();
    int v = (t < BINW) ? cnt[t] : 0;
    float di = rsqrtf((float)v + 1.0f);   // +1 = self loop
    if (t < BINW) base[t] = v;
    __syncthreads();
    for (int off = 1; off < BINW; off <<= 1) {
        int tv = (t >= off && t < BINW) ? base[t - off] : 0;
        __syncthreads();
        if (t < BINW) base[t] += tv;
        __syncthreads();
    }
    int excl = (t < BINW) ? (base[t] - v) : 0;
    __syncthreads();
    if (t < BINW) { base[t] = excl; cursor[t] = excl; }
    __syncthreads();
    for (int i = t; i < binsz; i += 256) {
        unsigned val = arr[i];
        int pos = atomicAdd(&cursor[val >> 24], 1);
        sorted_[pos] = (int)(val & 0xFFFFFF);
    }
    __syncthreads();
    for (int i = t; i < binsz; i += 256) srcidx[s0 + i] = sorted_[i];
    int node = b * BINW + t;
    if (t < BINW && node < N) {
        rowptr[node] = s0 + base[t];
        dinv[node] = di;
        pk[node] = make_int2(nt[node], __float_as_int(di));
    }
    if (b == NB - 1 && t == 0) rowptr[N] = s1;
}

// ---- per-edge packed operand in CSR order (layer 1: type[src], dinv[src]).
//      Also zeroes pool (replaces a memset launch; runs before agg3). ----
__global__ void k_buildepk(const int* __restrict__ srcidx, const int2* __restrict__ pk,
                           unsigned* __restrict__ epku, float* __restrict__ pool, int E) {
    int i = blockIdx.x * blockDim.x + threadIdx.x;
    if (i < NUM_GRAPHS * DD) pool[i] = 0.f;
    if (i >= E) return;
    int2 p = pk[srcidx[i]];
    epku[i] = ((unsigned)p.x << 16) |
              (unsigned)__half_as_ushort(__float2half(__int_as_float(p.y)));
}

// ---- embW1 = emb_table @ W1 ----
__global__ void k_embW1(const float* __restrict__ emb, const float* __restrict__ W1,
                        float* __restrict__ embW1, int V) {
    __shared__ float er[DD];
    int v = blockIdx.x, j = threadIdx.x;
    er[j] = emb[v * DD + j];
    __syncthreads();
    float acc = 0.0f;
    #pragma unroll
    for (int d = 0; d < DD; ++d) acc += er[d] * W1[d * DD + j];
    embW1[v * DD + j] = acc;
}

// ---- pack W (64x64 f32) into half2 pairs: Wpk[p*64+j] = {W[2p][j], W[2p+1][j]} ----
__global__ void k_packW(const float* __restrict__ W, unsigned* __restrict__ Wpk) {
    int t = blockIdx.x * blockDim.x + threadIdx.x;
    if (t >= 32 * DD) return;
    int p = t >> 6, j = t & 63;
    __half2 h = __floats2half2_rn(W[(2 * p) * DD + j], W[(2 * p + 1) * DD + j]);
    Wpk[t] = __builtin_bit_cast(unsigned, h);
}

// ======================= quarter-wave gather (4 groups x 16 lanes) ==========
// lane l owns features [4l,4l+4) via uint2 (8B); 4-deep per-lane load pipeline.
// accumulate via v_fma_mix (measured faster for agg3). NO index prefetch:
// agg3's nodes are adjacent so srcidx streams are L1-warm (round-11 lesson).
__device__ __forceinline__ void acc_h4(float4& a, uint2 r) {
    a.x = fmixlo(a.x, r.x); a.y = fmixhi(a.y, r.x);
    a.z = fmixlo(a.z, r.y); a.w = fmixhi(a.w, r.y);
}

// partial sum (NO cross-group reduce) — caller reduces when needed
__device__ __forceinline__ float4 gather_partial_q(const int* __restrict__ srcidx,
                                                   const __half* __restrict__ Hs,
                                                   int s, int e, int g, int l) {
    float4 A = {0,0,0,0}, B = {0,0,0,0}, C = {0,0,0,0}, D = {0,0,0,0};
    int k = s;
    int kend = s + ((e - s) & ~15);
    if (k < kend) {
        uint2 r0 = *(const uint2*)(Hs + (long)srcidx[k + g] * DD + 4 * l);
        uint2 r1 = *(const uint2*)(Hs + (long)srcidx[k + 4 + g] * DD + 4 * l);
        uint2 r2 = *(const uint2*)(Hs + (long)srcidx[k + 8 + g] * DD + 4 * l);
        uint2 r3 = *(const uint2*)(Hs + (long)srcidx[k + 12 + g] * DD + 4 * l);
        k += 16;
        for (; k < kend; k += 16) {
            uint2 n0 = *(const uint2*)(Hs + (long)srcidx[k + g] * DD + 4 * l);
            uint2 n1 = *(const uint2*)(Hs + (long)srcidx[k + 4 + g] * DD + 4 * l);
            uint2 n2 = *(const uint2*)(Hs + (long)srcidx[k + 8 + g] * DD + 4 * l);
            uint2 n3 = *(const uint2*)(Hs + (long)srcidx[k + 12 + g] * DD + 4 * l);
            acc_h4(A, r0); acc_h4(B, r1); acc_h4(C, r2); acc_h4(D, r3);
            r0 = n0; r1 = n1; r2 = n2; r3 = n3;
        }
        acc_h4(A, r0); acc_h4(B, r1); acc_h4(C, r2); acc_h4(D, r3);
    }
    for (; k < e; k += 4) {
        if (k + g < e) {
            uint2 rr = *(const uint2*)(Hs + (long)srcidx[k + g] * DD + 4 * l);
            acc_h4(A, rr);
        }
    }
    A.x += B.x + C.x + D.x; A.y += B.y + C.y + D.y;
    A.z += B.z + C.z + D.z; A.w += B.w + C.w + D.w;
    return A;
}

// ======================= eighth-wave gather (8 groups x 8 lanes) ============
// lane l owns features [8l,8l+8) via one uint4 (16B) load per row.
// cvt+add accumulate (measured faster than fma_mix for agg2: 59.1 vs 61.2 us).
__device__ __forceinline__ void acc_h8(float4& A, float4& B, uint4 r) {
    float2 f0 = __half22float2(*(const __half2*)&r.x);
    float2 f1 = __half22float2(*(const __half2*)&r.y);
    float2 f2 = __half22float2(*(const __half2*)&r.z);
    float2 f3 = __half22float2(*(const __half2*)&r.w);
    A.x += f0.x; A.y += f0.y; A.z += f1.x; A.w += f1.y;
    B.x += f2.x; B.y += f2.y; B.z += f3.x; B.w += f3.y;
}

// pi0/pi1 = srcidx[s+g], srcidx[s+8+g] (first round); pi2/pi3 = srcidx[q+g],
// srcidx[q+8+g] where q = s + ((e-s)&~15) — the TAIL indices, prefetched a
// full node ahead so the tail row loads have no srcidx->row serial hop.
// (Round-14 lesson: prefetching ROWS instead regresses — wasted speculative
//  traffic on deg<16 nodes; indices are cheap, rows are not.)
__device__ __forceinline__ void gather_sum_8p(const int* __restrict__ srcidx,
                                              const __half* __restrict__ Hs,
                                              int s, int e, int g, int l,
                                              float4& A, float4& B,
                                              int pi0, int pi1, int pi2, int pi3) {
    float4 A1 = {0.f, 0.f, 0.f, 0.f}, B1 = {0.f, 0.f, 0.f, 0.f};
    int k = s;
    int kend = s + ((e - s) & ~15);
    if (k < kend) {
        uint4 r0 = *(const uint4*)(Hs + (long)pi0 * DD + 8 * l);
        uint4 r1 = *(const uint4*)(Hs + (long)pi1 * DD + 8 * l);
        k += 16;
        for (; k < kend; k += 16) {
            uint4 n0 = *(const uint4*)(Hs + (long)srcidx[k + g] * DD + 8 * l);
            uint4 n1 = *(const uint4*)(Hs + (long)srcidx[k + 8 + g] * DD + 8 * l);
            acc_h8(A, B, r0);
            acc_h8(A1, B1, r1);
            r0 = n0; r1 = n1;
        }
        acc_h8(A, B, r0);
        acc_h8(A1, B1, r1);
    }
    if (k + 8 <= e) {                       // one more full round of 8 (idx prefetched)
        uint4 r = *(const uint4*)(Hs + (long)pi2 * DD + 8 * l);
        acc_h8(A, B, r);
        k += 8;
        pi2 = pi3;                          // tail (if any) uses the second tail index
    }
    if (k + g < e) {                        // tail < 8 edges (idx prefetched)
        uint4 r = *(const uint4*)(Hs + (long)pi2 * DD + 8 * l);
        acc_h8(A1, B1, r);
    }
    A.x += A1.x; A.y += A1.y; A.z += A1.z; A.w += A1.w;
    B.x += B1.x; B.y += B1.y; B.z += B1.z; B.w += B1.w;
}

// ---- layer-1, quarter-wave over LDS ew table; next-node epku prefetch
//      covering BOTH the first round (pu0/pu1) and the tail (pu2/pu3). ----
__global__ __launch_bounds__(256, 4) void k_agg1_fused(const int* __restrict__ rowptr,
                                                    const unsigned* __restrict__ epku,
                                                    const int2* __restrict__ pk,
                                                    const float* __restrict__ embW1,
                                                    const float* __restrict__ b1,
                                                    __half* __restrict__ OUT, int N, int V) {
    __shared__ float ew[30 * DD];
    int tid = threadIdx.x;
    for (int k = tid; k < V * DD; k += 256) ew[k] = embW1[k];
    __syncthreads();
    int lane = tid & 63;
    int g = lane >> 4, l = lane & 15;
    float4 bq = *(const float4*)(b1 + 4 * l);
    int wstride = gridDim.x * 4;
    int node = __builtin_amdgcn_readfirstlane(blockIdx.x * 4 + (tid >> 6));
    int s = 0, e = 0;
    unsigned pu0 = 0, pu1 = 0, pu2 = 0, pu3 = 0;
    if (node < N) {
        s = rowptr[node]; e = rowptr[node + 1];
        int q1 = s + ((e - s) & ~7);
        pu0 = epku[s + g];  pu1 = epku[s + 4 + g];    // unconditional (SPAD)
        pu2 = epku[q1 + g]; pu3 = epku[q1 + 4 + g];
    }
#define P8(U0, U1) { \
        unsigned _u0 = (U0), _u1 = (U1); \
        int _t0 = _u0 >> 16, _t1 = _u1 >> 16; \
        float _d0 = MDLO(_u0), _d1 = MDLO(_u1); \
        float4 _w0 = *(const float4*)(ew + _t0 * DD + 4 * l); \
        float4 _w1 = *(const float4*)(ew + _t1 * DD + 4 * l); \
        acc.x += _w0.x * _d0 + _w1.x * _d1; \
        acc.y += _w0.y * _d0 + _w1.y * _d1; \
        acc.z += _w0.z * _d0 + _w1.z * _d1; \
        acc.w += _w0.w * _d0 + _w1.w * _d1; }
#define P4(U0) { \
        unsigned _u0 = (U0); \
        int _t0 = _u0 >> 16; \
        float _d0 = MDLO(_u0); \
        float4 _w0 = *(const float4*)(ew + _t0 * DD + 4 * l); \
        acc.x += _w0.x * _d0; acc.y += _w0.y * _d0; \
        acc.z += _w0.z * _d0; acc.w += _w0.w * _d0; }
    while (node < N) {
        int nn = node + wstride;
        int ns = 0, ne = 0;
        if (nn < N) { ns = rowptr[nn]; ne = rowptr[nn + 1]; }
        int2 pc = pk[node];                       // epilogue data, off the chain
        float4 acc = {0.f, 0.f, 0.f, 0.f};
        int k = s;
        if (k + 8 <= e) {
            P8(pu0, pu1);
            k += 8;
            for (; k + 8 <= e; k += 8) P8(epku[k + g], epku[k + 4 + g]);
        }
        if (k + 4 <= e) { P4(pu2); k += 4; pu2 = pu3; }   // tail values prefetched
        if (k + g < e)  { P4(pu2); }
        unsigned npu0 = 0, npu1 = 0, npu2 = 0, npu3 = 0;  // next-node prefetch
        if (nn < N) {
            int q1 = ns + ((ne - ns) & ~7);
            npu0 = epku[ns + g];  npu1 = epku[ns + 4 + g];
            npu2 = epku[q1 + g];  npu3 = epku[q1 + 4 + g];
        }
        acc.x += __shfl_xor(acc.x, 16, 64); acc.x += __shfl_xor(acc.x, 32, 64);
        acc.y += __shfl_xor(acc.y, 16, 64); acc.y += __shfl_xor(acc.y, 32, 64);
        acc.z += __shfl_xor(acc.z, 16, 64); acc.z += __shfl_xor(acc.z, 32, 64);
        acc.w += __shfl_xor(acc.w, 16, 64); acc.w += __shfl_xor(acc.w, 32, 64);
        float dc = __int_as_float(pc.y);
        float4 wc = *(const float4*)(ew + pc.x * DD + 4 * l);
        float4 v;
        v.x = fmaxf((acc.x + wc.x * dc) * dc + bq.x, 0.f) * dc;
        v.y = fmaxf((acc.y + wc.y * dc) * dc + bq.y, 0.f) * dc;
        v.z = fmaxf((acc.z + wc.z * dc) * dc + bq.z, 0.f) * dc;
        v.w = fmaxf((acc.w + wc.w * dc) * dc + bq.w, 0.f) * dc;
        if (g == 0) {
            __half2 h0 = __floats2half2_rn(v.x, v.y);
            __half2 h1 = __floats2half2_rn(v.z, v.w);
            uint2 st;
            st.x = __builtin_bit_cast(unsigned, h0);
            st.y = __builtin_bit_cast(unsigned, h1);
            *(uint2*)(OUT + (long)node * DD + 4 * l) = st;
        }
        node = nn; s = ns; e = ne;
        pu0 = npu0; pu1 = npu1; pu2 = npu2; pu3 = npu3;
    }
#undef P8
#undef P4
}

// ---- layer-2: eighth-wave gather + W2 matmul; next-node srcidx prefetch
//      covering BOTH the first round and the tail (pi0..pi3). ----
__global__ __launch_bounds__(256, 4) void k_agg2_fused(const int* __restrict__ rowptr,
                                                    const int* __restrict__ srcidx,
                                                    const float* __restrict__ dinv,
                                                    const __half* __restrict__ Hs,
                                                    const float* __restrict__ b2,
                                                    const unsigned* __restrict__ W2pk,
                                                    __half* __restrict__ OUT, int N) {
    int tid = threadIdx.x;
    int lane = tid & 63;
    int g = lane >> 3, l = lane & 7;
    unsigned Wc[32];
    #pragma unroll
    for (int p = 0; p < 32; ++p) Wc[p] = W2pk[p * DD + lane];
    float bl = b2[lane];              // bias on OUTPUT feature (post-matmul)
    int wstride = gridDim.x * 4;
    int node = __builtin_amdgcn_readfirstlane(blockIdx.x * 4 + (tid >> 6));
    int s = 0, e = 0;
    int pi0 = 0, pi1 = 0, pi2 = 0, pi3 = 0;
    if (node < N) {
        s = rowptr[node]; e = rowptr[node + 1];
        int q = s + ((e - s) & ~15);
        pi0 = srcidx[s + g];  pi1 = srcidx[s + 8 + g];   // unconditional (SPAD)
        pi2 = srcidx[q + g];  pi3 = srcidx[q + 8 + g];
    }
    while (node < N) {
        int nn = node + wstride;
        int ns = 0, ne = 0;
        if (nn < N) { ns = rowptr[nn]; ne = rowptr[nn + 1]; }   // prefetch next node
        float dc = dinv[node];                                   // prefetch epilogue data
        uint4 sr = *(const uint4*)(Hs + (long)node * DD + 8 * l);
        float4 A = {0.f, 0.f, 0.f, 0.f}, B = {0.f, 0.f, 0.f, 0.f};
        gather_sum_8p(srcidx, Hs, s, e, g, l, A, B, pi0, pi1, pi2, pi3);
        int npi0 = 0, npi1 = 0, npi2 = 0, npi3 = 0;   // next-node idx prefetch
        if (nn < N) {
            int qn = ns + ((ne - ns) & ~15);
            npi0 = srcidx[ns + g];  npi1 = srcidx[ns + 8 + g];
            npi2 = srcidx[qn + g];  npi3 = srcidx[qn + 8 + g];
        }
        // reduce across the 8 groups (g = lane bits 3..5)
        #pragma unroll
        for (int m = 8; m <= 32; m <<= 1) {
            A.x += __shfl_xor(A.x, m, 64); A.y += __shfl_xor(A.y, m, 64);
            A.z += __shfl_xor(A.z, m, 64); A.w += __shfl_xor(A.w, m, 64);
            B.x += __shfl_xor(B.x, m, 64); B.y += __shfl_xor(B.y, m, 64);
            B.z += __shfl_xor(B.z, m, 64); B.w += __shfl_xor(B.w, m, 64);
        }
        float2 s0 = __half22float2(*(const __half2*)&sr.x);
        float2 s1 = __half22float2(*(const __half2*)&sr.y);
        float2 s2 = __half22float2(*(const __half2*)&sr.z);
        float2 s3 = __half22float2(*(const __half2*)&sr.w);
        float t0 = (A.x + s0.x) * dc, t1 = (A.y + s0.y) * dc;
        float t2 = (A.z + s1.x) * dc, t3 = (A.w + s1.y) * dc;
        float t4 = (B.x + s2.x) * dc, t5 = (B.y + s2.y) * dc;
        float t6 = (B.z + s3.x) * dc, t7 = (B.w + s3.y) * dc;
        // pack: lane l (0..7) holds pairs (t[8l+2q], t[8l+2q+1]) in vp[q]
        int vp0 = __builtin_bit_cast(int, __floats2half2_rn(t0, t1));
        int vp1 = __builtin_bit_cast(int, __floats2half2_rn(t2, t3));
        int vp2 = __builtin_bit_cast(int, __floats2half2_rn(t4, t5));
        int vp3 = __builtin_bit_cast(int, __floats2half2_rn(t6, t7));
        // (t @ W2)[lane]: pair p lives in lane p>>2, slot p&3
        float o0 = 0.f, o1 = 0.f, o2 = 0.f, o3 = 0.f;
        #pragma unroll
        for (int p = 0; p < 32; p += 4) {
            o0 = fdot2u((unsigned)__builtin_amdgcn_readlane(vp0, p >> 2), Wc[p + 0], o0);
            o1 = fdot2u((unsigned)__builtin_amdgcn_readlane(vp1, p >> 2), Wc[p + 1], o1);
            o2 = fdot2u((unsigned)__builtin_amdgcn_readlane(vp2, p >> 2), Wc[p + 2], o2);
            o3 = fdot2u((unsigned)__builtin_amdgcn_readlane(vp3, p >> 2), Wc[p + 3], o3);
        }
        float u = (o0 + o1) + (o2 + o3);
        float v2 = fmaxf(u + bl, 0.f);
        OUT[(long)node * DD + lane] = __float2half(v2 * dc);   // v2s = v2*dinv
        node = nn; s = ns; e = ne;
        pi0 = npi0; pi1 = npi1; pi2 = npi2; pi3 = npi3;
    }
}

// ---- reduce per-group (4-group) pool partials, then atomics (g==0 lanes) ----
__device__ __forceinline__ void flush_pool_q(float4& PA, float* __restrict__ pool,
                                             int gcur, int g, int l) {
    gcur &= (NUM_GRAPHS - 1);   // defensive: guarantees in-bounds atomic target
    PA.x += __shfl_xor(PA.x, 16, 64); PA.x += __shfl_xor(PA.x, 32, 64);
    PA.y += __shfl_xor(PA.y, 16, 64); PA.y += __shfl_xor(PA.y, 32, 64);
    PA.z += __shfl_xor(PA.z, 16, 64); PA.z += __shfl_xor(PA.z, 32, 64);
    PA.w += __shfl_xor(PA.w, 16, 64); PA.w += __shfl_xor(PA.w, 32, 64);
    if (g == 0) {
        atomicAdd(&pool[gcur * DD + 4 * l + 0], PA.x);
        atomicAdd(&pool[gcur * DD + 4 * l + 1], PA.y);
        atomicAdd(&pool[gcur * DD + 4 * l + 2], PA.z);
        atomicAdd(&pool[gcur * DD + 4 * l + 3], PA.w);
    }
}

// ---- layer-3 + pooling in v2-space: y = dc*(Σ v2s + self); pool[batch] += y.
//      Quarter-wave gather (4-deep load pipeline, known-good round-10 form) +
//      per-group partial pool accumulators. ----
__global__ __launch_bounds__(256, 4) void k_agg3_pool(const int* __restrict__ rowptr,
                                                   const int* __restrict__ srcidx,
                                                   const float* __restrict__ dinv,
                                                   const __half* __restrict__ Hs,
                                                   const int* __restrict__ batch,
                                                   float* __restrict__ pool,
                                                   int N, int chunk) {
    int tid = threadIdx.x;
    int lane = tid & 63;
    int g = lane >> 4, l = lane & 15;
    int w = __builtin_amdgcn_readfirstlane(blockIdx.x * 4 + (tid >> 6));
    int start = w * chunk;
    if (start >= N) return;
    int endn = min(N, start + chunk);
    int gcur = batch[start];
    float4 PA = {0.f, 0.f, 0.f, 0.f};
    int s = rowptr[start];                 // contiguous chunk: s = previous e
    for (int node = start; node < endn; ++node) {
        int e = rowptr[node + 1];
        float dc = dinv[node];
        int gb = batch[node];
        uint2 sr = *(const uint2*)(Hs + (long)node * DD + 4 * l);  // early, overlaps gather
        float4 A = gather_partial_q(srcidx, Hs, s, e, g, l);
        if (g == 0) {                      // add self exactly once (group 0)
            A.x = fmixlo(A.x, sr.x); A.y = fmixhi(A.y, sr.x);
            A.z = fmixlo(A.z, sr.y); A.w = fmixhi(A.w, sr.y);
        }
        if (gb != gcur) {
            flush_pool_q(PA, pool, gcur, g, l);
            gcur = gb;
            PA.x = dc * A.x; PA.y = dc * A.y; PA.z = dc * A.z; PA.w = dc * A.w;
        } else {
            PA.x += dc * A.x; PA.y += dc * A.y; PA.z += dc * A.z; PA.w += dc * A.w;
        }
        s = e;
    }
    flush_pool_q(PA, pool, gcur, g, l);
}

// ---- final: per-graph W3 matmul (f32) + b3, mean, L2 normalize ----
__global__ void k_final(const float* __restrict__ pool, const int* __restrict__ batch,
                        const float* __restrict__ W3, const float* __restrict__ b3,
                        float* __restrict__ out, int N) {
    __shared__ float pr[DD];
    int g = blockIdx.x, j = threadIdx.x;
    pr[j] = pool[g * DD + j];
    __syncthreads();
    int lo = 0, hi = N;
    while (lo < hi) { int m = (lo + hi) >> 1; if (batch[m] < g) lo = m + 1; else hi = m; }
    int lo2 = lo; hi = N;
    while (lo2 < hi) { int m = (lo2 + hi) >> 1; if (batch[m] < g + 1) lo2 = m + 1; else hi = m; }
    float cnt = fmaxf((float)(lo2 - lo), 1.0f);
    float acc = 0.0f;
    #pragma unroll
    for (int d = 0; d < DD; ++d) acc += pr[d] * W3[d * DD + j];
    float v = acc / cnt + b3[j];
    float sq = v * v;
    #pragma unroll
    for (int off = 32; off > 0; off >>= 1) sq += __shfl_down(sq, off, 64);
    float nrm = __shfl(sq, 0, 64);
    out[g * DD + j] = v / sqrtf(nrm);
}

extern "C" void kernel_launch(void* const* d_in, const int* in_sizes, int n_in,
                              void* d_out, int out_size, void* d_ws, size_t ws_size,
                              hipStream_t stream) {
    const int*   node_types = (const int*)d_in[0];
    const int*   edge_index = (const int*)d_in[1];
    const int*   batch      = (const int*)d_in[2];
    const float* emb        = (const float*)d_in[3];
    const float* W1 = (const float*)d_in[4];
    const float* b1 = (const float*)d_in[5];
    const float* W2 = (const float*)d_in[6];
    const float* b2 = (const float*)d_in[7];
    const float* W3 = (const float*)d_in[8];
    const float* b3 = (const float*)d_in[9];
    const int N = in_sizes[0];
    const int E = in_sizes[1] / 2;
    const int V = in_sizes[3] / DD;
    const int* row = edge_index;
    const int* col = edge_index + E;
    const long ND = (long)N * DD;
    const int NB = (N + BINW - 1) / BINW;
    const int CE = (E + EB - 1) / EB;

    // workspace layout (srcidx/epku padded +SPAD for unconditional prefetch)
    char* p = (char*)d_ws;
    __half*   hsA     = (__half*)p;       p += ND * sizeof(__half);
    __half*   hsB     = (__half*)p;       p += ND * sizeof(__half);
    int*      srcidx  = (int*)p;          p += (size_t)(E + SPAD) * sizeof(int);
    unsigned* epku    = (unsigned*)p;     p += (size_t)(E + SPAD) * sizeof(unsigned);
    unsigned* binned  = (unsigned*)p;     p += (size_t)E * sizeof(unsigned);
    int*      H       = (int*)p;          p += (size_t)EB * NB * sizeof(int);
    int*      bintot  = (int*)p;          p += (size_t)(NB + 4) * sizeof(int);
    int*      binstart= (int*)p;          p += (size_t)(NB + 4) * sizeof(int);
    float*    dinv    = (float*)p;        p += (size_t)N * sizeof(float);
    int2*     pk      = (int2*)p;         p += (size_t)N * sizeof(int2);
    int*      rowptr  = (int*)p;          p += (size_t)(N + 4) * sizeof(int);
    float*    pool    = (float*)p;        p += (size_t)NUM_GRAPHS * DD * sizeof(float);
    float*    embW1   = (float*)p;        p += (size_t)V * DD * sizeof(float);
    unsigned* W2pk    = (unsigned*)p;     p += 32 * DD * sizeof(unsigned);

    // ---- atomic-free sort-based CSR build (srcidx pad zeroed in k_scanB;
    //      pool zeroed in k_buildepk — no separate memset launches) ----
    k_hist<<<EB, 256, 0, stream>>>(col, H, E, NB, CE);
    k_scanA<<<NB, 256, 0, stream>>>(H, bintot, NB);
    k_scanB<<<1, 512, 0, stream>>>(bintot, binstart, srcidx, E, NB);
    k_scatbin<<<EB, 256, 0, stream>>>(row, col, H, binstart, binned, E, NB, CE);
    k_bincsr<<<NB, 256, 0, stream>>>(binned, binstart, node_types, srcidx, rowptr,
                                     dinv, pk, N, NB);
    k_buildepk<<<(E + 255) / 256, 256, 0, stream>>>(srcidx, pk, epku, pool, E);

    // ---- weight prep ----
    k_embW1<<<V, DD, 0, stream>>>(emb, W1, embW1, V);
    k_packW<<<8, 256, 0, stream>>>(W2, W2pk);

    // ---- layer 1 -> v1s fp16 (quarter-wave, no matmul) ----
    k_agg1_fused<<<AGG_BLOCKS, 256, 0, stream>>>(rowptr, epku, pk, embW1, b1,
                                                 hsA, N, V);
    // ---- layer 2: gather + W2 post-agg -> v2s fp16 ----
    k_agg2_fused<<<AGG_BLOCKS, 256, 0, stream>>>(rowptr, srcidx, dinv, hsA, b2, W2pk,
                                                 hsB, N);
    // ---- layer 3 + pooling in v2-space ----
    const int totalWaves = AGG_BLOCKS * 4;
    const int chunk = (N + totalWaves - 1) / totalWaves;
    k_agg3_pool<<<AGG_BLOCKS, 256, 0, stream>>>(rowptr, srcidx, dinv, hsB, batch,
                                                pool, N, chunk);
    // ---- per-graph W3 + b3 + mean + normalize ----
    k_final<<<NUM_GRAPHS, DD, 0, stream>>>(pool, batch, W3, b3, (float*)d_out, N);
}